// Round 1
// 120.805 us; speedup vs baseline: 1.0134x; 1.0134x over previous
//
#include <hip/hip_runtime.h>

typedef __attribute__((ext_vector_type(4))) float f32x4;
typedef __attribute__((ext_vector_type(8))) short bf16x8;
typedef __attribute__((ext_vector_type(4))) short bf16x4;
typedef long fp8x8;   // 8 packed e4m3 bytes (i64 MFMA operand)

#define NH 4

// round-to-nearest-even f32 -> bf16
static __device__ __forceinline__ unsigned short f2bf(float f){
  unsigned u = __float_as_uint(f);
  u += 0x7FFFu + ((u >> 16) & 1u);
  return (unsigned short)(u >> 16);
}

// pack two f32 -> two bf16 (round-half-up) in one uint (low = a)
static __device__ __forceinline__ unsigned pack2bf(float a, float b){
  return __builtin_amdgcn_perm(__float_as_uint(b) + 0x8000u,
                               __float_as_uint(a) + 0x8000u, 0x07060302u);
}

// pack two f32 -> two bf16 TRUNCATING (1 v_perm). Used only for P: the same
// truncated P feeds both O=P*V and l=P*1, so the truncation bias cancels.
static __device__ __forceinline__ unsigned pack2bf_t(float a, float b){
  return __builtin_amdgcn_perm(__float_as_uint(b), __float_as_uint(a), 0x07060302u);
}

// pack 4 floats into 4 fp8(e4m3) bytes of one int (byte0 = a)
static __device__ __forceinline__ int pack_fp8x4(float a, float b, float c, float d){
  int w = __builtin_amdgcn_cvt_pk_fp8_f32(a, b, 0, false);
  w     = __builtin_amdgcn_cvt_pk_fp8_f32(c, d, w, true);
  return w;
}

// ---------------- weight-prep kernel (runs once per launch, 4 blocks) ------
// Per head: builds bf16 MFMA fragment-order W in ws + scaled biases.
// WF[h][s][lane][8bf16]:
//   s 0..7  = Wq^T A-frags (s=et*2+ks, pre-scaled S1):
//             lane(quad,l16) = Wq[ks*32+quad*8+j][et*16+l16], j=0..7
//   s 8..15 = Wk^T A-frags (s-8=ft*2+ks, pre-scaled S1): same mapping
//   s 16,17 = Wv B-frags: lane(quad,l16) = Wv[ks*32+quad*8+j][l16]
// bias_s[h][0..63]=bq*S1, [64..127]=bk*S1.
__global__ __launch_bounds__(256) void wprep_kernel(
    const float* __restrict__ Wq, const float* __restrict__ bq,
    const float* __restrict__ Wk, const float* __restrict__ bk,
    const float* __restrict__ Wv,
    unsigned short* __restrict__ WF, float* __restrict__ bias_s, int n)
{
  __shared__ unsigned short wqT[64*72];  // [e][f], stride 72 (16B-aligned rows)
  __shared__ unsigned short wkT[64*72];
  __shared__ unsigned short wvT[16*72];  // [d][f]

  const int t = threadIdx.x;     // 0..255
  const int h = blockIdx.x;
  const float S1 = 0.4246609001f; // sqrt((1/sqrt(64)) * log2(e))
  const int f = t >> 2, eg = t & 3;

  {
    const float4* g = (const float4*)(Wq + h*4096 + f*64 + eg*16);
    #pragma unroll
    for (int p = 0; p < 4; ++p){
      float4 d = g[p];
      int e0 = eg*16 + p*4;
      wqT[(e0+0)*72 + f] = f2bf(d.x * S1);
      wqT[(e0+1)*72 + f] = f2bf(d.y * S1);
      wqT[(e0+2)*72 + f] = f2bf(d.z * S1);
      wqT[(e0+3)*72 + f] = f2bf(d.w * S1);
    }
  }
  {
    const float4* g = (const float4*)(Wk + h*4096 + f*64 + eg*16);
    #pragma unroll
    for (int p = 0; p < 4; ++p){
      float4 d = g[p];
      int e0 = eg*16 + p*4;
      wkT[(e0+0)*72 + f] = f2bf(d.x * S1);
      wkT[(e0+1)*72 + f] = f2bf(d.y * S1);
      wkT[(e0+2)*72 + f] = f2bf(d.z * S1);
      wkT[(e0+3)*72 + f] = f2bf(d.w * S1);
    }
  }
  {
    float4 d = *(const float4*)(Wv + h*1024 + f*16 + eg*4);
    int d0 = eg*4;
    wvT[(d0+0)*72 + f] = f2bf(d.x);
    wvT[(d0+1)*72 + f] = f2bf(d.y);
    wvT[(d0+2)*72 + f] = f2bf(d.z);
    wvT[(d0+3)*72 + f] = f2bf(d.w);
  }
  if (t < 64)       bias_s[h*128 + t] = bq[h*64 + t] * S1;
  else if (t < 128) bias_s[h*128 + t] = bk[h*64 + (t-64)] * S1;
  __syncthreads();

  const int lane = t & 63, w = t >> 6;
  const int quad = lane >> 4, l16 = lane & 15;
  for (int s = w; s < 18; s += 4){
    const unsigned short* src;
    if (s < 8){      int et = s>>1,     ks = s&1;     src = wqT + (et*16+l16)*72 + ks*32 + quad*8; }
    else if (s < 16){int ft = (s-8)>>1, ks = (s-8)&1; src = wkT + (ft*16+l16)*72 + ks*32 + quad*8; }
    else {           int ks = s-16;                   src = wvT + l16*72 + ks*32 + quad*8; }
    uint4 v = *(const uint4*)src;
    *(uint4*)(WF + ((size_t)(h*18 + s)*64 + lane)*8) = v;
  }
}

// ---------------- projection kernel (MFMA) ----------------
// grid (n/64, NH), block 256 = 4 waves. Per wave: Q^T (e-tile w, 4 row-tiles),
// K^T (f-tile w, 4 key-tiles), V (row-tile w). Epilogue writes Qfr/Kt/Vt in
// fragment-tile order so ALL attn hot/prologue loads are dense.
// R16: Vt is now written CHUNK-interleaved (chunk C = pair of 16-key tiles):
// lane frag of tile T lands at (C*64+lane)*16B + (T&1)*8B, so attn's K=32 PV
// B-operand (32-key V frag) is ONE dense 16B load per lane.
__global__ __launch_bounds__(256) void proj_kernel(
    const float* __restrict__ x, const float* __restrict__ bv,
    const unsigned short* __restrict__ WF, const float* __restrict__ bias_s,
    unsigned char* __restrict__ Qfr, unsigned char* __restrict__ Kt,
    unsigned short* __restrict__ Vt, int n)
{
  __shared__ unsigned short xf[8*64*8];  // x frags: [it*2+ks][lane][8bf16]
  __shared__ float bql[64], bkl[64], bvl[16];

  const int t  = threadIdx.x;
  const int h  = blockIdx.y;
  const int r0 = blockIdx.x * 64;

  // stage x tile -> bf16 fragment order
  {
    const int r = t >> 2, cg4 = t & 3;
    const float4* g = (const float4*)(x + (size_t)(r0 + r)*64 + cg4*16);
    float4 a = g[0], b = g[1], c = g[2], d = g[3];
    unsigned u0 = pack2bf(a.x,a.y), u1 = pack2bf(a.z,a.w);
    unsigned u2 = pack2bf(b.x,b.y), u3 = pack2bf(b.z,b.w);
    unsigned u4 = pack2bf(c.x,c.y), u5 = pack2bf(c.z,c.w);
    unsigned u6 = pack2bf(d.x,d.y), u7 = pack2bf(d.z,d.w);
    const int it = r >> 4, l16r = r & 15, ks = cg4 >> 1, q0 = (cg4 & 1)*2;
    uint4* dst0 = (uint4*)(xf + ((it*2+ks)*64 + q0*16     + l16r)*8);
    uint4* dst1 = (uint4*)(xf + ((it*2+ks)*64 + (q0+1)*16 + l16r)*8);
    *dst0 = make_uint4(u0,u1,u2,u3);
    *dst1 = make_uint4(u4,u5,u6,u7);
  }
  if (t < 64)        bql[t]     = bias_s[h*128 + t];
  else if (t < 128)  bkl[t-64]  = bias_s[h*128 + t];
  else if (t < 144)  bvl[t-128] = bv[h*16 + (t-128)];
  __syncthreads();

  const int lane = t & 63, w = t >> 6;
  const int quad = lane >> 4, l16 = lane & 15;

  bf16x8 xa[8];
  #pragma unroll
  for (int i = 0; i < 8; ++i)
    xa[i] = *(const bf16x8*)(xf + (i*64 + lane)*8);

  const unsigned short* WFh = WF + (size_t)h*18*64*8;
  bf16x8 wq0 = *(const bf16x8*)(WFh + ((size_t)(     w*2 + 0)*64 + lane)*8);
  bf16x8 wq1 = *(const bf16x8*)(WFh + ((size_t)(     w*2 + 1)*64 + lane)*8);
  bf16x8 wk0 = *(const bf16x8*)(WFh + ((size_t)(8  + w*2 + 0)*64 + lane)*8);
  bf16x8 wk1 = *(const bf16x8*)(WFh + ((size_t)(8  + w*2 + 1)*64 + lane)*8);
  bf16x8 wv0 = *(const bf16x8*)(WFh + ((size_t)16*64 + lane)*8);
  bf16x8 wv1 = *(const bf16x8*)(WFh + ((size_t)17*64 + lane)*8);

  const f32x4 z = {0.f,0.f,0.f,0.f};
  f32x4 accQ[4] = {z,z,z,z};   // Q^T: rows e (tile w), cols Q-row (tile it)
  f32x4 accK[4] = {z,z,z,z};   // K^T: rows f (tile w), cols key (tile tt)
  f32x4 accV = z;

  #pragma unroll
  for (int it = 0; it < 4; ++it){
    accQ[it] = __builtin_amdgcn_mfma_f32_16x16x32_bf16(wq0, xa[it*2+0], accQ[it], 0,0,0);
    accQ[it] = __builtin_amdgcn_mfma_f32_16x16x32_bf16(wq1, xa[it*2+1], accQ[it], 0,0,0);
  }
  #pragma unroll
  for (int tt = 0; tt < 4; ++tt){
    accK[tt] = __builtin_amdgcn_mfma_f32_16x16x32_bf16(wk0, xa[tt*2+0], accK[tt], 0,0,0);
    accK[tt] = __builtin_amdgcn_mfma_f32_16x16x32_bf16(wk1, xa[tt*2+1], accK[tt], 0,0,0);
  }
  accV = __builtin_amdgcn_mfma_f32_16x16x32_bf16(xa[w*2+0], wv0, accV, 0,0,0);
  accV = __builtin_amdgcn_mfma_f32_16x16x32_bf16(xa[w*2+1], wv1, accV, 0,0,0);

  // ---- Q^T tiles: C[e=quad*4+reg (+w*16)][Qrow=l16] -> Qfr frag bytes
  {
    const int e0 = w*16 + quad*4;
    const float b0 = bql[e0], b1 = bql[e0+1], b2 = bql[e0+2], b3 = bql[e0+3];
    const int qk = (e0 & 31) >> 3, hf = e0 >> 5, boff = (quad & 1) * 4;
    #pragma unroll
    for (int it = 0; it < 4; ++it){
      unsigned o = pack_fp8x4(accQ[it][0]+b0, accQ[it][1]+b1,
                              accQ[it][2]+b2, accQ[it][3]+b3);
      const int T = (r0 >> 4) + it;
      *(unsigned*)(Qfr + (size_t)h*((size_t)n<<6) + (size_t)T*1024
                       + (qk*16 + l16)*16 + hf*8 + boff) = o;
    }
  }
  // ---- K^T tiles: C[f=quad*4+reg (+w*16)][key=l16] -> Kt frag bytes
  {
    const int f0 = w*16 + quad*4;
    const float bk0 = bkl[f0], bk1 = bkl[f0+1], bk2 = bkl[f0+2], bk3 = bkl[f0+3];
    const int qk = (f0 & 31) >> 3, hf = f0 >> 5, boff = (quad & 1) * 4;
    #pragma unroll
    for (int tt = 0; tt < 4; ++tt){
      unsigned o = pack_fp8x4(accK[tt][0]+bk0, accK[tt][1]+bk1,
                              accK[tt][2]+bk2, accK[tt][3]+bk3);
      const int T = (r0 >> 4) + tt;
      *(unsigned*)(Kt + (size_t)h*((size_t)n<<6) + (size_t)T*1024
                      + (qk*16 + l16)*16 + hf*8 + boff) = o;
    }
  }
  // ---- V tile (it=w): C[key=quad*4+reg][d=l16] == Vt lane(quad,l16), j=reg.
  // Chunk-interleaved store: chunk C=T>>1, half=(T&1) -> 8B slot within the
  // lane's 16B K=32 frag.
  {
    float bvv = bvl[l16];
    unsigned v01 = pack2bf(accV[0]+bvv, accV[1]+bvv);
    unsigned v23 = pack2bf(accV[2]+bvv, accV[3]+bvv);
    const int T = (r0 >> 4) + w;
    *(uint2*)(Vt + (size_t)h*((size_t)n<<4)
                 + ((size_t)(T>>1)*64 + lane)*8 + (T&1)*4) = make_uint2(v01, v23);
  }
}

// ---------------- flash attention kernel ----------------
// grid (n/32)*NH, block 512 = 8 waves = jq 0..7 (key split 8-way), all waves
// share the block's 32 Q-rows. All loads dense (fragment-ordered Qfr/Kt/Vt).
// Max-free online softmax; row sums via ones-MFMA (C-layout == O).
// R16: K=32 PV. Each 32-key CHUNK = two 16-key S-tiles whose lane-local P
// packs concatenate into one 16x16x32 bf16 A-frag (key enumeration
// k=quad*8+j, j<4 from tile A, j>=4 from tile B -- pure relabeling, softmax
// is permutation-invariant over keys). V frag = one dense uint4 (proj
// interleaves tile pairs). Per 32 keys: 12 MFMA + 3 loads vs R15's
// 16 MFMA + 4 loads; PV/la run on the full-rate K=32 shape instead of the
// half-rate 16x16x16 legacy shape (matrix cycles -25%).
// launch_bounds min-waves 8->4: measured occupancy was already ~4-5
// waves/SIMD; the 64-VGPR cap was what made earlier K=32-PV attempts spill.
__global__ __launch_bounds__(512, 4) void attn_kernel(
    const unsigned char* __restrict__ Qfr, const unsigned char* __restrict__ Kt,
    const unsigned short* __restrict__ Vt, float* __restrict__ out, int n)
{
  __shared__ float part[7][64][17];   // 30.5 KB padded

  const int tid  = threadIdx.x;
  const int lane = tid & 63;
  const int jq   = tid >> 6;     // 0..7: key-range octant
  const int bid  = blockIdx.x;
  const int h    = bid & 3;
  const int iblk = bid >> 2;
  const int l16  = lane & 15, quad = lane >> 4;
  const int i0   = iblk*32;
  const int ntq  = (n >> 3) >> 4;            // 16-key tiles per octant (64)
  const int nch  = ntq >> 1;                 // 32-key chunks per octant (32)
  const int tile0 = jq * ntq;

  // Q fragments: 2 i-tiles x 2 e-halves -- DENSE (one uint4 per i-tile)
  const unsigned char* qfh = Qfr + (size_t)h*((size_t)n<<6);
  longlong2 q0 = *(const longlong2*)(qfh + (size_t)((i0>>4)    )*1024 + lane*16);
  longlong2 q1 = *(const longlong2*)(qfh + (size_t)((i0>>4) + 1)*1024 + lane*16);
  const fp8x8 qf00 = (fp8x8)q0.x;
  const fp8x8 qf01 = (fp8x8)q0.y;
  const fp8x8 qf10 = (fp8x8)q1.x;
  const fp8x8 qf11 = (fp8x8)q1.y;

  const longlong2* ktl = (const longlong2*)(Kt + (size_t)h*((size_t)n<<6)) + (size_t)tile0*64 + lane;
  const uint4*     vtu = (const uint4*)(Vt + (size_t)h*((size_t)n<<4)) + (size_t)(tile0>>1)*64 + lane;

  f32x4 o0  = {0.f,0.f,0.f,0.f};
  f32x4 o1  = {0.f,0.f,0.f,0.f};
  f32x4 la0 = {0.f,0.f,0.f,0.f};
  f32x4 la1 = {0.f,0.f,0.f,0.f};
  const f32x4 z = {0.f,0.f,0.f,0.f};
  const bf16x8 vones = {(short)0x3F80, (short)0x3F80, (short)0x3F80, (short)0x3F80,
                        (short)0x3F80, (short)0x3F80, (short)0x3F80, (short)0x3F80};

  // prologue: chunk c (tiles 2c,2c+1) and chunk c+1 in regs
  longlong2 ka0 = ktl[0],   ka1 = ktl[64];
  uint4     va  = vtu[0];
  longlong2 kb0 = ktl[128], kb1 = ktl[192];
  uint4     vb  = vtu[64];

#define ATTN_CHUNK(KA, KB, VV)                                                \
  {                                                                           \
    fp8x8 a0 = (fp8x8)KA.x;                                                   \
    fp8x8 a1 = (fp8x8)KA.y;                                                   \
    fp8x8 b0 = (fp8x8)KB.x;                                                   \
    fp8x8 b1 = (fp8x8)KB.y;                                                   \
    f32x4 s0 = __builtin_amdgcn_mfma_f32_16x16x32_fp8_fp8(a0, qf00, z, 0,0,0);\
    s0 = __builtin_amdgcn_mfma_f32_16x16x32_fp8_fp8(a1, qf01, s0, 0,0,0);     \
    f32x4 s1 = __builtin_amdgcn_mfma_f32_16x16x32_fp8_fp8(a0, qf10, z, 0,0,0);\
    s1 = __builtin_amdgcn_mfma_f32_16x16x32_fp8_fp8(a1, qf11, s1, 0,0,0);     \
    f32x4 t0 = __builtin_amdgcn_mfma_f32_16x16x32_fp8_fp8(b0, qf00, z, 0,0,0);\
    t0 = __builtin_amdgcn_mfma_f32_16x16x32_fp8_fp8(b1, qf01, t0, 0,0,0);     \
    f32x4 t1 = __builtin_amdgcn_mfma_f32_16x16x32_fp8_fp8(b0, qf10, z, 0,0,0);\
    t1 = __builtin_amdgcn_mfma_f32_16x16x32_fp8_fp8(b1, qf11, t1, 0,0,0);     \
    float pa00 = __builtin_amdgcn_exp2f(s0[0]);                               \
    float pa01 = __builtin_amdgcn_exp2f(s0[1]);                               \
    float pa02 = __builtin_amdgcn_exp2f(s0[2]);                               \
    float pa03 = __builtin_amdgcn_exp2f(s0[3]);                               \
    float pa10 = __builtin_amdgcn_exp2f(s1[0]);                               \
    float pa11 = __builtin_amdgcn_exp2f(s1[1]);                               \
    float pa12 = __builtin_amdgcn_exp2f(s1[2]);                               \
    float pa13 = __builtin_amdgcn_exp2f(s1[3]);                               \
    float pb00 = __builtin_amdgcn_exp2f(t0[0]);                               \
    float pb01 = __builtin_amdgcn_exp2f(t0[1]);                               \
    float pb02 = __builtin_amdgcn_exp2f(t0[2]);                               \
    float pb03 = __builtin_amdgcn_exp2f(t0[3]);                               \
    float pb10 = __builtin_amdgcn_exp2f(t1[0]);                               \
    float pb11 = __builtin_amdgcn_exp2f(t1[1]);                               \
    float pb12 = __builtin_amdgcn_exp2f(t1[2]);                               \
    float pb13 = __builtin_amdgcn_exp2f(t1[3]);                               \
    union { uint4 u; bf16x8 v; } pq0, pq1, vfu;                               \
    pq0.u = make_uint4(pack2bf_t(pa00,pa01), pack2bf_t(pa02,pa03),            \
                       pack2bf_t(pb00,pb01), pack2bf_t(pb02,pb03));           \
    pq1.u = make_uint4(pack2bf_t(pa10,pa11), pack2bf_t(pa12,pa13),            \
                       pack2bf_t(pb10,pb11), pack2bf_t(pb12,pb13));           \
    vfu.u = VV;                                                               \
    o0  = __builtin_amdgcn_mfma_f32_16x16x32_bf16(pq0.v, vfu.v, o0,  0,0,0);  \
    o1  = __builtin_amdgcn_mfma_f32_16x16x32_bf16(pq1.v, vfu.v, o1,  0,0,0);  \
    la0 = __builtin_amdgcn_mfma_f32_16x16x32_bf16(pq0.v, vones, la0, 0,0,0);  \
    la1 = __builtin_amdgcn_mfma_f32_16x16x32_bf16(pq1.v, vones, la1, 0,0,0);  \
  }

  // main loop: prefetch 2 chunks ahead at fixed offsets, pointer bump
  for (int c = 0; c < nch - 2; ++c){
    longlong2 kc0 = ktl[256], kc1 = ktl[320];
    uint4     vc  = vtu[128];
    ATTN_CHUNK(ka0, ka1, va)
    ka0 = kb0; ka1 = kb1; va = vb;
    kb0 = kc0; kb1 = kc1; vb = vc;
    ktl += 128; vtu += 64;
  }
  // tail: last two chunks, no prefetch
  ATTN_CHUNK(ka0, ka1, va)
  ATTN_CHUNK(kb0, kb1, vb)
#undef ATTN_CHUNK

  if (jq > 0){
    float* p = &part[jq-1][lane][0];
    p[ 0]=o0[0];  p[ 1]=o0[1];  p[ 2]=o0[2];  p[ 3]=o0[3];
    p[ 4]=o1[0];  p[ 5]=o1[1];  p[ 6]=o1[2];  p[ 7]=o1[3];
    p[ 8]=la0[0]; p[ 9]=la0[1]; p[10]=la0[2]; p[11]=la0[3];
    p[12]=la1[0]; p[13]=la1[1]; p[14]=la1[2]; p[15]=la1[3];
  }
  __syncthreads();

  if (jq == 0){
    #pragma unroll
    for (int q = 0; q < 7; ++q){
      const float* r = &part[q][lane][0];
      o0[0] +=r[0];  o0[1] +=r[1];  o0[2] +=r[2];  o0[3] +=r[3];
      o1[0] +=r[4];  o1[1] +=r[5];  o1[2] +=r[6];  o1[3] +=r[7];
      la0[0]+=r[8];  la0[1]+=r[9];  la0[2]+=r[10]; la0[3]+=r[11];
      la1[0]+=r[12]; la1[1]+=r[13]; la1[2]+=r[14]; la1[3]+=r[15];
    }
    #pragma unroll
    for (int reg = 0; reg < 4; ++reg){
      int i = quad*4 + reg;
      out[(size_t)(i0 + i)*64      + h*16 + l16] = o0[reg] / la0[reg];
      out[(size_t)(i0 + 16 + i)*64 + h*16 + l16] = o1[reg] / la1[reg];
    }
  }
}

extern "C" void kernel_launch(void* const* d_in, const int* in_sizes, int n_in,
                              void* d_out, int out_size, void* d_ws, size_t ws_size,
                              hipStream_t stream) {
  const float* x  = (const float*)d_in[0];
  const float* Wq = (const float*)d_in[1];
  const float* bq = (const float*)d_in[2];
  const float* Wk = (const float*)d_in[3];
  const float* bk = (const float*)d_in[4];
  const float* Wv = (const float*)d_in[5];
  const float* bv = (const float*)d_in[6];
  float* out = (float*)d_out;

  const int n = in_sizes[0] / 64;   // 8192

  unsigned char* Qfr  = (unsigned char*)d_ws;                       // NH*n*64 B frag tiles (Q)
  unsigned char* Kt   = Qfr + (size_t)NH*n*64;                      // NH*n*64 B frag tiles (K)
  unsigned short* Vt  = (unsigned short*)(Kt + (size_t)NH*n*64);    // NH*n*16 u16 frag tiles (chunk-interleaved)
  unsigned short* WF  = Vt + (size_t)NH*n*16;                       // NH*18*64*8 u16 frags
  float* bias_s       = (float*)(WF + (size_t)NH*18*64*8);          // NH*128 f32

  wprep_kernel<<<NH, 256, 0, stream>>>(Wq, bq, Wk, bk, Wv, WF, bias_s, n);
  proj_kernel<<<dim3(n/64, NH), 256, 0, stream>>>(x, bv, WF, bias_s, Qfr, Kt, Vt, n);
  attn_kernel<<<dim3((n/32)*NH), 512, 0, stream>>>(Qfr, Kt, Vt, out, n);
}

// Round 2
// 118.036 us; speedup vs baseline: 1.0372x; 1.0235x over previous
//
#include <hip/hip_runtime.h>

typedef __attribute__((ext_vector_type(4))) float f32x4;
typedef __attribute__((ext_vector_type(8))) short bf16x8;
typedef __attribute__((ext_vector_type(4))) short bf16x4;
typedef long fp8x8;   // 8 packed e4m3 bytes (i64 MFMA operand)

#define NH 4

// round-to-nearest-even f32 -> bf16
static __device__ __forceinline__ unsigned short f2bf(float f){
  unsigned u = __float_as_uint(f);
  u += 0x7FFFu + ((u >> 16) & 1u);
  return (unsigned short)(u >> 16);
}

// pack two f32 -> two bf16 (round-half-up) in one uint (low = a)
static __device__ __forceinline__ unsigned pack2bf(float a, float b){
  return __builtin_amdgcn_perm(__float_as_uint(b) + 0x8000u,
                               __float_as_uint(a) + 0x8000u, 0x07060302u);
}

// pack two f32 -> two bf16 TRUNCATING (1 v_perm). Used only for P: the same
// truncated P feeds both O=P*V and l=P*1, so the truncation bias cancels.
static __device__ __forceinline__ unsigned pack2bf_t(float a, float b){
  return __builtin_amdgcn_perm(__float_as_uint(b), __float_as_uint(a), 0x07060302u);
}

// pack 4 floats into 4 fp8(e4m3) bytes of one int (byte0 = a)
static __device__ __forceinline__ int pack_fp8x4(float a, float b, float c, float d){
  int w = __builtin_amdgcn_cvt_pk_fp8_f32(a, b, 0, false);
  w     = __builtin_amdgcn_cvt_pk_fp8_f32(c, d, w, true);
  return w;
}

// ---------------- weight-prep kernel (runs once per launch, 4 blocks) ------
// Per head: builds bf16 MFMA fragment-order W in ws + scaled biases.
// WF[h][s][lane][8bf16]:
//   s 0..7  = Wq^T A-frags (s=et*2+ks, pre-scaled S1):
//             lane(quad,l16) = Wq[ks*32+quad*8+j][et*16+l16], j=0..7
//   s 8..15 = Wk^T A-frags (s-8=ft*2+ks, pre-scaled S1): same mapping
//   s 16,17 = Wv B-frags: lane(quad,l16) = Wv[ks*32+quad*8+j][l16]
// bias_s[h][0..63]=bq*S1, [64..127]=bk*S1.
__global__ __launch_bounds__(256) void wprep_kernel(
    const float* __restrict__ Wq, const float* __restrict__ bq,
    const float* __restrict__ Wk, const float* __restrict__ bk,
    const float* __restrict__ Wv,
    unsigned short* __restrict__ WF, float* __restrict__ bias_s, int n)
{
  __shared__ unsigned short wqT[64*72];  // [e][f], stride 72 (16B-aligned rows)
  __shared__ unsigned short wkT[64*72];
  __shared__ unsigned short wvT[16*72];  // [d][f]

  const int t = threadIdx.x;     // 0..255
  const int h = blockIdx.x;
  const float S1 = 0.4246609001f; // sqrt((1/sqrt(64)) * log2(e))
  const int f = t >> 2, eg = t & 3;

  {
    const float4* g = (const float4*)(Wq + h*4096 + f*64 + eg*16);
    #pragma unroll
    for (int p = 0; p < 4; ++p){
      float4 d = g[p];
      int e0 = eg*16 + p*4;
      wqT[(e0+0)*72 + f] = f2bf(d.x * S1);
      wqT[(e0+1)*72 + f] = f2bf(d.y * S1);
      wqT[(e0+2)*72 + f] = f2bf(d.z * S1);
      wqT[(e0+3)*72 + f] = f2bf(d.w * S1);
    }
  }
  {
    const float4* g = (const float4*)(Wk + h*4096 + f*64 + eg*16);
    #pragma unroll
    for (int p = 0; p < 4; ++p){
      float4 d = g[p];
      int e0 = eg*16 + p*4;
      wkT[(e0+0)*72 + f] = f2bf(d.x * S1);
      wkT[(e0+1)*72 + f] = f2bf(d.y * S1);
      wkT[(e0+2)*72 + f] = f2bf(d.z * S1);
      wkT[(e0+3)*72 + f] = f2bf(d.w * S1);
    }
  }
  {
    float4 d = *(const float4*)(Wv + h*1024 + f*16 + eg*4);
    int d0 = eg*4;
    wvT[(d0+0)*72 + f] = f2bf(d.x);
    wvT[(d0+1)*72 + f] = f2bf(d.y);
    wvT[(d0+2)*72 + f] = f2bf(d.z);
    wvT[(d0+3)*72 + f] = f2bf(d.w);
  }
  if (t < 64)       bias_s[h*128 + t] = bq[h*64 + t] * S1;
  else if (t < 128) bias_s[h*128 + t] = bk[h*64 + (t-64)] * S1;
  __syncthreads();

  const int lane = t & 63, w = t >> 6;
  const int quad = lane >> 4, l16 = lane & 15;
  for (int s = w; s < 18; s += 4){
    const unsigned short* src;
    if (s < 8){      int et = s>>1,     ks = s&1;     src = wqT + (et*16+l16)*72 + ks*32 + quad*8; }
    else if (s < 16){int ft = (s-8)>>1, ks = (s-8)&1; src = wkT + (ft*16+l16)*72 + ks*32 + quad*8; }
    else {           int ks = s-16;                   src = wvT + l16*72 + ks*32 + quad*8; }
    uint4 v = *(const uint4*)src;
    *(uint4*)(WF + ((size_t)(h*18 + s)*64 + lane)*8) = v;
  }
}

// ---------------- projection kernel (MFMA) ----------------
// grid (n/64, NH), block 256 = 4 waves. Per wave: Q^T (e-tile w, 4 row-tiles),
// K^T (f-tile w, 4 key-tiles), V (row-tile w). Epilogue writes Qfr/Kt/Vt in
// fragment-tile order so ALL attn hot/prologue loads are dense.
// Vt is written CHUNK-interleaved (chunk C = pair of 16-key tiles):
// lane frag of tile T lands at (C*64+lane)*16B + (T&1)*8B, so attn's K=32 PV
// B-operand (32-key V frag) is ONE dense 16B load per lane.
__global__ __launch_bounds__(256) void proj_kernel(
    const float* __restrict__ x, const float* __restrict__ bv,
    const unsigned short* __restrict__ WF, const float* __restrict__ bias_s,
    unsigned char* __restrict__ Qfr, unsigned char* __restrict__ Kt,
    unsigned short* __restrict__ Vt, int n)
{
  __shared__ unsigned short xf[8*64*8];  // x frags: [it*2+ks][lane][8bf16]
  __shared__ float bql[64], bkl[64], bvl[16];

  const int t  = threadIdx.x;
  const int h  = blockIdx.y;
  const int r0 = blockIdx.x * 64;

  // stage x tile -> bf16 fragment order
  {
    const int r = t >> 2, cg4 = t & 3;
    const float4* g = (const float4*)(x + (size_t)(r0 + r)*64 + cg4*16);
    float4 a = g[0], b = g[1], c = g[2], d = g[3];
    unsigned u0 = pack2bf(a.x,a.y), u1 = pack2bf(a.z,a.w);
    unsigned u2 = pack2bf(b.x,b.y), u3 = pack2bf(b.z,b.w);
    unsigned u4 = pack2bf(c.x,c.y), u5 = pack2bf(c.z,c.w);
    unsigned u6 = pack2bf(d.x,d.y), u7 = pack2bf(d.z,d.w);
    const int it = r >> 4, l16r = r & 15, ks = cg4 >> 1, q0 = (cg4 & 1)*2;
    uint4* dst0 = (uint4*)(xf + ((it*2+ks)*64 + q0*16     + l16r)*8);
    uint4* dst1 = (uint4*)(xf + ((it*2+ks)*64 + (q0+1)*16 + l16r)*8);
    *dst0 = make_uint4(u0,u1,u2,u3);
    *dst1 = make_uint4(u4,u5,u6,u7);
  }
  if (t < 64)        bql[t]     = bias_s[h*128 + t];
  else if (t < 128)  bkl[t-64]  = bias_s[h*128 + t];
  else if (t < 144)  bvl[t-128] = bv[h*16 + (t-128)];
  __syncthreads();

  const int lane = t & 63, w = t >> 6;
  const int quad = lane >> 4, l16 = lane & 15;

  bf16x8 xa[8];
  #pragma unroll
  for (int i = 0; i < 8; ++i)
    xa[i] = *(const bf16x8*)(xf + (i*64 + lane)*8);

  const unsigned short* WFh = WF + (size_t)h*18*64*8;
  bf16x8 wq0 = *(const bf16x8*)(WFh + ((size_t)(     w*2 + 0)*64 + lane)*8);
  bf16x8 wq1 = *(const bf16x8*)(WFh + ((size_t)(     w*2 + 1)*64 + lane)*8);
  bf16x8 wk0 = *(const bf16x8*)(WFh + ((size_t)(8  + w*2 + 0)*64 + lane)*8);
  bf16x8 wk1 = *(const bf16x8*)(WFh + ((size_t)(8  + w*2 + 1)*64 + lane)*8);
  bf16x8 wv0 = *(const bf16x8*)(WFh + ((size_t)16*64 + lane)*8);
  bf16x8 wv1 = *(const bf16x8*)(WFh + ((size_t)17*64 + lane)*8);

  const f32x4 z = {0.f,0.f,0.f,0.f};
  f32x4 accQ[4] = {z,z,z,z};   // Q^T: rows e (tile w), cols Q-row (tile it)
  f32x4 accK[4] = {z,z,z,z};   // K^T: rows f (tile w), cols key (tile tt)
  f32x4 accV = z;

  #pragma unroll
  for (int it = 0; it < 4; ++it){
    accQ[it] = __builtin_amdgcn_mfma_f32_16x16x32_bf16(wq0, xa[it*2+0], accQ[it], 0,0,0);
    accQ[it] = __builtin_amdgcn_mfma_f32_16x16x32_bf16(wq1, xa[it*2+1], accQ[it], 0,0,0);
  }
  #pragma unroll
  for (int tt = 0; tt < 4; ++tt){
    accK[tt] = __builtin_amdgcn_mfma_f32_16x16x32_bf16(wk0, xa[tt*2+0], accK[tt], 0,0,0);
    accK[tt] = __builtin_amdgcn_mfma_f32_16x16x32_bf16(wk1, xa[tt*2+1], accK[tt], 0,0,0);
  }
  accV = __builtin_amdgcn_mfma_f32_16x16x32_bf16(xa[w*2+0], wv0, accV, 0,0,0);
  accV = __builtin_amdgcn_mfma_f32_16x16x32_bf16(xa[w*2+1], wv1, accV, 0,0,0);

  // ---- Q^T tiles: C[e=quad*4+reg (+w*16)][Qrow=l16] -> Qfr frag bytes
  {
    const int e0 = w*16 + quad*4;
    const float b0 = bql[e0], b1 = bql[e0+1], b2 = bql[e0+2], b3 = bql[e0+3];
    const int qk = (e0 & 31) >> 3, hf = e0 >> 5, boff = (quad & 1) * 4;
    #pragma unroll
    for (int it = 0; it < 4; ++it){
      unsigned o = pack_fp8x4(accQ[it][0]+b0, accQ[it][1]+b1,
                              accQ[it][2]+b2, accQ[it][3]+b3);
      const int T = (r0 >> 4) + it;
      *(unsigned*)(Qfr + (size_t)h*((size_t)n<<6) + (size_t)T*1024
                       + (qk*16 + l16)*16 + hf*8 + boff) = o;
    }
  }
  // ---- K^T tiles: C[f=quad*4+reg (+w*16)][key=l16] -> Kt frag bytes
  {
    const int f0 = w*16 + quad*4;
    const float bk0 = bkl[f0], bk1 = bkl[f0+1], bk2 = bkl[f0+2], bk3 = bkl[f0+3];
    const int qk = (f0 & 31) >> 3, hf = f0 >> 5, boff = (quad & 1) * 4;
    #pragma unroll
    for (int tt = 0; tt < 4; ++tt){
      unsigned o = pack_fp8x4(accK[tt][0]+bk0, accK[tt][1]+bk1,
                              accK[tt][2]+bk2, accK[tt][3]+bk3);
      const int T = (r0 >> 4) + tt;
      *(unsigned*)(Kt + (size_t)h*((size_t)n<<6) + (size_t)T*1024
                      + (qk*16 + l16)*16 + hf*8 + boff) = o;
    }
  }
  // ---- V tile (it=w): C[key=quad*4+reg][d=l16] == Vt lane(quad,l16), j=reg.
  // Chunk-interleaved store: chunk C=T>>1, half=(T&1) -> 8B slot within the
  // lane's 16B K=32 frag.
  {
    float bvv = bvl[l16];
    unsigned v01 = pack2bf(accV[0]+bvv, accV[1]+bvv);
    unsigned v23 = pack2bf(accV[2]+bvv, accV[3]+bvv);
    const int T = (r0 >> 4) + w;
    *(uint2*)(Vt + (size_t)h*((size_t)n<<4)
                 + ((size_t)(T>>1)*64 + lane)*8 + (T&1)*4) = make_uint2(v01, v23);
  }
}

// ---------------- flash attention kernel ----------------
// grid (n/32)*NH, block 512 = 8 waves = jq 0..7 (key split 8-way), all waves
// share the block's 32 Q-rows. All loads dense (fragment-ordered Qfr/Kt/Vt).
// Max-free online softmax; row sums via ones-MFMA (C-layout == O).
// K=32 PV: each 32-key CHUNK = two 16-key S-tiles whose lane-local P packs
// concatenate into one 16x16x32 bf16 A-frag (pure key relabeling; softmax is
// permutation-invariant over keys). V frag = one dense uint4.
// R17: ISSUE-PORT diet. R16 post-mortem: per-SIMD issue slots were the
// binding resource (56 issues/chunk x 8 waves ~= 1.04/cyc vs 1.0 capacity;
// MfmaUtil 45 + VALUBusy 58, neither pipe saturated). The rolling
// double-buffer (ka=kb;va=vb) cost 12 v_mov/chunk. Unroll-by-2 with loads
// issued DIRECTLY into the just-consumed register set kills all moves, the
// kc/vc temporaries (-12 live VGPRs), and halves pointer/loop bookkeeping.
// Prefetch distance stays 2 chunks (~400 cyc >> L2 latency ~200 cyc).
__global__ __launch_bounds__(512, 4) void attn_kernel(
    const unsigned char* __restrict__ Qfr, const unsigned char* __restrict__ Kt,
    const unsigned short* __restrict__ Vt, float* __restrict__ out, int n)
{
  __shared__ float part[7][64][17];   // 30.5 KB padded

  const int tid  = threadIdx.x;
  const int lane = tid & 63;
  const int jq   = tid >> 6;     // 0..7: key-range octant
  const int bid  = blockIdx.x;
  const int h    = bid & 3;
  const int iblk = bid >> 2;
  const int l16  = lane & 15, quad = lane >> 4;
  const int i0   = iblk*32;
  const int ntq  = (n >> 3) >> 4;            // 16-key tiles per octant (64)
  const int nch  = ntq >> 1;                 // 32-key chunks per octant (32)
  const int tile0 = jq * ntq;

  // Q fragments: 2 i-tiles x 2 e-halves -- DENSE (one uint4 per i-tile)
  const unsigned char* qfh = Qfr + (size_t)h*((size_t)n<<6);
  longlong2 q0 = *(const longlong2*)(qfh + (size_t)((i0>>4)    )*1024 + lane*16);
  longlong2 q1 = *(const longlong2*)(qfh + (size_t)((i0>>4) + 1)*1024 + lane*16);
  const fp8x8 qf00 = (fp8x8)q0.x;
  const fp8x8 qf01 = (fp8x8)q0.y;
  const fp8x8 qf10 = (fp8x8)q1.x;
  const fp8x8 qf11 = (fp8x8)q1.y;

  const longlong2* ktl = (const longlong2*)(Kt + (size_t)h*((size_t)n<<6)) + (size_t)tile0*64 + lane;
  const uint4*     vtu = (const uint4*)(Vt + (size_t)h*((size_t)n<<4)) + (size_t)(tile0>>1)*64 + lane;

  f32x4 o0  = {0.f,0.f,0.f,0.f};
  f32x4 o1  = {0.f,0.f,0.f,0.f};
  f32x4 la0 = {0.f,0.f,0.f,0.f};
  f32x4 la1 = {0.f,0.f,0.f,0.f};
  const f32x4 z = {0.f,0.f,0.f,0.f};
  const bf16x8 vones = {(short)0x3F80, (short)0x3F80, (short)0x3F80, (short)0x3F80,
                        (short)0x3F80, (short)0x3F80, (short)0x3F80, (short)0x3F80};

  // prologue: chunk 0 in A regs, chunk 1 in B regs
  longlong2 ka0 = ktl[0],   ka1 = ktl[64];
  uint4     va  = vtu[0];
  longlong2 kb0 = ktl[128], kb1 = ktl[192];
  uint4     vb  = vtu[64];

#define ATTN_CHUNK(KA, KB, VV)                                                \
  {                                                                           \
    fp8x8 a0 = (fp8x8)KA.x;                                                   \
    fp8x8 a1 = (fp8x8)KA.y;                                                   \
    fp8x8 b0 = (fp8x8)KB.x;                                                   \
    fp8x8 b1 = (fp8x8)KB.y;                                                   \
    f32x4 s0 = __builtin_amdgcn_mfma_f32_16x16x32_fp8_fp8(a0, qf00, z, 0,0,0);\
    s0 = __builtin_amdgcn_mfma_f32_16x16x32_fp8_fp8(a1, qf01, s0, 0,0,0);     \
    f32x4 s1 = __builtin_amdgcn_mfma_f32_16x16x32_fp8_fp8(a0, qf10, z, 0,0,0);\
    s1 = __builtin_amdgcn_mfma_f32_16x16x32_fp8_fp8(a1, qf11, s1, 0,0,0);     \
    f32x4 t0 = __builtin_amdgcn_mfma_f32_16x16x32_fp8_fp8(b0, qf00, z, 0,0,0);\
    t0 = __builtin_amdgcn_mfma_f32_16x16x32_fp8_fp8(b1, qf01, t0, 0,0,0);     \
    f32x4 t1 = __builtin_amdgcn_mfma_f32_16x16x32_fp8_fp8(b0, qf10, z, 0,0,0);\
    t1 = __builtin_amdgcn_mfma_f32_16x16x32_fp8_fp8(b1, qf11, t1, 0,0,0);     \
    float pa00 = __builtin_amdgcn_exp2f(s0[0]);                               \
    float pa01 = __builtin_amdgcn_exp2f(s0[1]);                               \
    float pa02 = __builtin_amdgcn_exp2f(s0[2]);                               \
    float pa03 = __builtin_amdgcn_exp2f(s0[3]);                               \
    float pa10 = __builtin_amdgcn_exp2f(s1[0]);                               \
    float pa11 = __builtin_amdgcn_exp2f(s1[1]);                               \
    float pa12 = __builtin_amdgcn_exp2f(s1[2]);                               \
    float pa13 = __builtin_amdgcn_exp2f(s1[3]);                               \
    float pb00 = __builtin_amdgcn_exp2f(t0[0]);                               \
    float pb01 = __builtin_amdgcn_exp2f(t0[1]);                               \
    float pb02 = __builtin_amdgcn_exp2f(t0[2]);                               \
    float pb03 = __builtin_amdgcn_exp2f(t0[3]);                               \
    float pb10 = __builtin_amdgcn_exp2f(t1[0]);                               \
    float pb11 = __builtin_amdgcn_exp2f(t1[1]);                               \
    float pb12 = __builtin_amdgcn_exp2f(t1[2]);                               \
    float pb13 = __builtin_amdgcn_exp2f(t1[3]);                               \
    union { uint4 u; bf16x8 v; } pq0, pq1, vfu;                               \
    pq0.u = make_uint4(pack2bf_t(pa00,pa01), pack2bf_t(pa02,pa03),            \
                       pack2bf_t(pb00,pb01), pack2bf_t(pb02,pb03));           \
    pq1.u = make_uint4(pack2bf_t(pa10,pa11), pack2bf_t(pa12,pa13),            \
                       pack2bf_t(pb10,pb11), pack2bf_t(pb12,pb13));           \
    vfu.u = VV;                                                               \
    o0  = __builtin_amdgcn_mfma_f32_16x16x32_bf16(pq0.v, vfu.v, o0,  0,0,0);  \
    o1  = __builtin_amdgcn_mfma_f32_16x16x32_bf16(pq1.v, vfu.v, o1,  0,0,0);  \
    la0 = __builtin_amdgcn_mfma_f32_16x16x32_bf16(pq0.v, vones, la0, 0,0,0);  \
    la1 = __builtin_amdgcn_mfma_f32_16x16x32_bf16(pq1.v, vones, la1, 0,0,0);  \
  }

  // main loop, unrolled x2: process chunk c from A regs then reload A with
  // chunk c+2 (ktl[256] = 2 chunks ahead of base); same for B with c+1/c+3.
  // No register moves, one pointer bump per 2 chunks.
  for (int c = 0; c < nch - 2; c += 2){
    ATTN_CHUNK(ka0, ka1, va)
    ka0 = ktl[256]; ka1 = ktl[320]; va = vtu[128];
    ATTN_CHUNK(kb0, kb1, vb)
    kb0 = ktl[384]; kb1 = ktl[448]; vb = vtu[192];
    ktl += 256; vtu += 128;
  }
  // tail: last two chunks, no prefetch
  ATTN_CHUNK(ka0, ka1, va)
  ATTN_CHUNK(kb0, kb1, vb)
#undef ATTN_CHUNK

  if (jq > 0){
    float* p = &part[jq-1][lane][0];
    p[ 0]=o0[0];  p[ 1]=o0[1];  p[ 2]=o0[2];  p[ 3]=o0[3];
    p[ 4]=o1[0];  p[ 5]=o1[1];  p[ 6]=o1[2];  p[ 7]=o1[3];
    p[ 8]=la0[0]; p[ 9]=la0[1]; p[10]=la0[2]; p[11]=la0[3];
    p[12]=la1[0]; p[13]=la1[1]; p[14]=la1[2]; p[15]=la1[3];
  }
  __syncthreads();

  if (jq == 0){
    #pragma unroll
    for (int q = 0; q < 7; ++q){
      const float* r = &part[q][lane][0];
      o0[0] +=r[0];  o0[1] +=r[1];  o0[2] +=r[2];  o0[3] +=r[3];
      o1[0] +=r[4];  o1[1] +=r[5];  o1[2] +=r[6];  o1[3] +=r[7];
      la0[0]+=r[8];  la0[1]+=r[9];  la0[2]+=r[10]; la0[3]+=r[11];
      la1[0]+=r[12]; la1[1]+=r[13]; la1[2]+=r[14]; la1[3]+=r[15];
    }
    #pragma unroll
    for (int reg = 0; reg < 4; ++reg){
      int i = quad*4 + reg;
      out[(size_t)(i0 + i)*64      + h*16 + l16] = o0[reg] / la0[reg];
      out[(size_t)(i0 + 16 + i)*64 + h*16 + l16] = o1[reg] / la1[reg];
    }
  }
}

extern "C" void kernel_launch(void* const* d_in, const int* in_sizes, int n_in,
                              void* d_out, int out_size, void* d_ws, size_t ws_size,
                              hipStream_t stream) {
  const float* x  = (const float*)d_in[0];
  const float* Wq = (const float*)d_in[1];
  const float* bq = (const float*)d_in[2];
  const float* Wk = (const float*)d_in[3];
  const float* bk = (const float*)d_in[4];
  const float* Wv = (const float*)d_in[5];
  const float* bv = (const float*)d_in[6];
  float* out = (float*)d_out;

  const int n = in_sizes[0] / 64;   // 8192

  unsigned char* Qfr  = (unsigned char*)d_ws;                       // NH*n*64 B frag tiles (Q)
  unsigned char* Kt   = Qfr + (size_t)NH*n*64;                      // NH*n*64 B frag tiles (K)
  unsigned short* Vt  = (unsigned short*)(Kt + (size_t)NH*n*64);    // NH*n*16 u16 frag tiles (chunk-interleaved)
  unsigned short* WF  = Vt + (size_t)NH*n*16;                       // NH*18*64*8 u16 frags
  float* bias_s       = (float*)(WF + (size_t)NH*18*64*8);          // NH*128 f32

  wprep_kernel<<<NH, 256, 0, stream>>>(Wq, bq, Wk, bk, Wv, WF, bias_s, n);
  proj_kernel<<<dim3(n/64, NH), 256, 0, stream>>>(x, bv, WF, bias_s, Qfr, Kt, Vt, n);
  attn_kernel<<<dim3((n/32)*NH), 512, 0, stream>>>(Qfr, Kt, Vt, out, n);
}

// Round 3
// 117.598 us; speedup vs baseline: 1.0411x; 1.0037x over previous
//
#include <hip/hip_runtime.h>

typedef __attribute__((ext_vector_type(4))) float f32x4;
typedef __attribute__((ext_vector_type(8))) short bf16x8;
typedef __attribute__((ext_vector_type(4))) short bf16x4;
typedef long fp8x8;   // 8 packed e4m3 bytes (i64 MFMA operand)

#define NH 4

// round-to-nearest-even f32 -> bf16
static __device__ __forceinline__ unsigned short f2bf(float f){
  unsigned u = __float_as_uint(f);
  u += 0x7FFFu + ((u >> 16) & 1u);
  return (unsigned short)(u >> 16);
}

// pack two f32 -> two bf16 (round-half-up) in one uint (low = a)
static __device__ __forceinline__ unsigned pack2bf(float a, float b){
  return __builtin_amdgcn_perm(__float_as_uint(b) + 0x8000u,
                               __float_as_uint(a) + 0x8000u, 0x07060302u);
}

// pack two f32 -> two bf16 TRUNCATING (1 v_perm). Used only for P: the same
// truncated P feeds both O=P*V and l=P*1, so the truncation bias cancels.
static __device__ __forceinline__ unsigned pack2bf_t(float a, float b){
  return __builtin_amdgcn_perm(__float_as_uint(b), __float_as_uint(a), 0x07060302u);
}

// pack 4 floats into 4 fp8(e4m3) bytes of one int (byte0 = a)
static __device__ __forceinline__ int pack_fp8x4(float a, float b, float c, float d){
  int w = __builtin_amdgcn_cvt_pk_fp8_f32(a, b, 0, false);
  w     = __builtin_amdgcn_cvt_pk_fp8_f32(c, d, w, true);
  return w;
}

// ---------------- weight-prep kernel (runs once per launch, 4 blocks) ------
// Per head: builds bf16 MFMA fragment-order W in ws + scaled biases.
// WF[h][s][lane][8bf16]:
//   s 0..7  = Wq^T A-frags (s=et*2+ks, pre-scaled S1):
//             lane(quad,l16) = Wq[ks*32+quad*8+j][et*16+l16], j=0..7
//   s 8..15 = Wk^T A-frags (s-8=ft*2+ks, pre-scaled S1): same mapping
//   s 16,17 = Wv B-frags: lane(quad,l16) = Wv[ks*32+quad*8+j][l16]
// bias_s[h][0..63]=bq*S1, [64..127]=bk*S1.
__global__ __launch_bounds__(256) void wprep_kernel(
    const float* __restrict__ Wq, const float* __restrict__ bq,
    const float* __restrict__ Wk, const float* __restrict__ bk,
    const float* __restrict__ Wv,
    unsigned short* __restrict__ WF, float* __restrict__ bias_s, int n)
{
  __shared__ unsigned short wqT[64*72];  // [e][f], stride 72 (16B-aligned rows)
  __shared__ unsigned short wkT[64*72];
  __shared__ unsigned short wvT[16*72];  // [d][f]

  const int t = threadIdx.x;     // 0..255
  const int h = blockIdx.x;
  const float S1 = 0.4246609001f; // sqrt((1/sqrt(64)) * log2(e))
  const int f = t >> 2, eg = t & 3;

  {
    const float4* g = (const float4*)(Wq + h*4096 + f*64 + eg*16);
    #pragma unroll
    for (int p = 0; p < 4; ++p){
      float4 d = g[p];
      int e0 = eg*16 + p*4;
      wqT[(e0+0)*72 + f] = f2bf(d.x * S1);
      wqT[(e0+1)*72 + f] = f2bf(d.y * S1);
      wqT[(e0+2)*72 + f] = f2bf(d.z * S1);
      wqT[(e0+3)*72 + f] = f2bf(d.w * S1);
    }
  }
  {
    const float4* g = (const float4*)(Wk + h*4096 + f*64 + eg*16);
    #pragma unroll
    for (int p = 0; p < 4; ++p){
      float4 d = g[p];
      int e0 = eg*16 + p*4;
      wkT[(e0+0)*72 + f] = f2bf(d.x * S1);
      wkT[(e0+1)*72 + f] = f2bf(d.y * S1);
      wkT[(e0+2)*72 + f] = f2bf(d.z * S1);
      wkT[(e0+3)*72 + f] = f2bf(d.w * S1);
    }
  }
  {
    float4 d = *(const float4*)(Wv + h*1024 + f*16 + eg*4);
    int d0 = eg*4;
    wvT[(d0+0)*72 + f] = f2bf(d.x);
    wvT[(d0+1)*72 + f] = f2bf(d.y);
    wvT[(d0+2)*72 + f] = f2bf(d.z);
    wvT[(d0+3)*72 + f] = f2bf(d.w);
  }
  if (t < 64)       bias_s[h*128 + t] = bq[h*64 + t] * S1;
  else if (t < 128) bias_s[h*128 + t] = bk[h*64 + (t-64)] * S1;
  __syncthreads();

  const int lane = t & 63, w = t >> 6;
  const int quad = lane >> 4, l16 = lane & 15;
  for (int s = w; s < 18; s += 4){
    const unsigned short* src;
    if (s < 8){      int et = s>>1,     ks = s&1;     src = wqT + (et*16+l16)*72 + ks*32 + quad*8; }
    else if (s < 16){int ft = (s-8)>>1, ks = (s-8)&1; src = wkT + (ft*16+l16)*72 + ks*32 + quad*8; }
    else {           int ks = s-16;                   src = wvT + l16*72 + ks*32 + quad*8; }
    uint4 v = *(const uint4*)src;
    *(uint4*)(WF + ((size_t)(h*18 + s)*64 + lane)*8) = v;
  }
}

// ---------------- projection kernel (MFMA) ----------------
// grid (n/64, NH), block 256 = 4 waves. Per wave: Q^T (e-tile w, 4 row-tiles),
// K^T (f-tile w, 4 key-tiles), V (row-tile w). Epilogue writes Qfr/Kt/Vt in
// fragment-tile order so ALL attn hot/prologue loads are dense.
// Vt is written CHUNK-interleaved (chunk C = pair of 16-key tiles):
// lane frag of tile T lands at (C*64+lane)*16B + (T&1)*8B, so attn's K=32 PV
// B-operand (32-key V frag) is ONE dense 16B load per lane.
__global__ __launch_bounds__(256) void proj_kernel(
    const float* __restrict__ x, const float* __restrict__ bv,
    const unsigned short* __restrict__ WF, const float* __restrict__ bias_s,
    unsigned char* __restrict__ Qfr, unsigned char* __restrict__ Kt,
    unsigned short* __restrict__ Vt, int n)
{
  __shared__ unsigned short xf[8*64*8];  // x frags: [it*2+ks][lane][8bf16]
  __shared__ float bql[64], bkl[64], bvl[16];

  const int t  = threadIdx.x;
  const int h  = blockIdx.y;
  const int r0 = blockIdx.x * 64;

  // stage x tile -> bf16 fragment order
  {
    const int r = t >> 2, cg4 = t & 3;
    const float4* g = (const float4*)(x + (size_t)(r0 + r)*64 + cg4*16);
    float4 a = g[0], b = g[1], c = g[2], d = g[3];
    unsigned u0 = pack2bf(a.x,a.y), u1 = pack2bf(a.z,a.w);
    unsigned u2 = pack2bf(b.x,b.y), u3 = pack2bf(b.z,b.w);
    unsigned u4 = pack2bf(c.x,c.y), u5 = pack2bf(c.z,c.w);
    unsigned u6 = pack2bf(d.x,d.y), u7 = pack2bf(d.z,d.w);
    const int it = r >> 4, l16r = r & 15, ks = cg4 >> 1, q0 = (cg4 & 1)*2;
    uint4* dst0 = (uint4*)(xf + ((it*2+ks)*64 + q0*16     + l16r)*8);
    uint4* dst1 = (uint4*)(xf + ((it*2+ks)*64 + (q0+1)*16 + l16r)*8);
    *dst0 = make_uint4(u0,u1,u2,u3);
    *dst1 = make_uint4(u4,u5,u6,u7);
  }
  if (t < 64)        bql[t]     = bias_s[h*128 + t];
  else if (t < 128)  bkl[t-64]  = bias_s[h*128 + t];
  else if (t < 144)  bvl[t-128] = bv[h*16 + (t-128)];
  __syncthreads();

  const int lane = t & 63, w = t >> 6;
  const int quad = lane >> 4, l16 = lane & 15;

  bf16x8 xa[8];
  #pragma unroll
  for (int i = 0; i < 8; ++i)
    xa[i] = *(const bf16x8*)(xf + (i*64 + lane)*8);

  const unsigned short* WFh = WF + (size_t)h*18*64*8;
  bf16x8 wq0 = *(const bf16x8*)(WFh + ((size_t)(     w*2 + 0)*64 + lane)*8);
  bf16x8 wq1 = *(const bf16x8*)(WFh + ((size_t)(     w*2 + 1)*64 + lane)*8);
  bf16x8 wk0 = *(const bf16x8*)(WFh + ((size_t)(8  + w*2 + 0)*64 + lane)*8);
  bf16x8 wk1 = *(const bf16x8*)(WFh + ((size_t)(8  + w*2 + 1)*64 + lane)*8);
  bf16x8 wv0 = *(const bf16x8*)(WFh + ((size_t)16*64 + lane)*8);
  bf16x8 wv1 = *(const bf16x8*)(WFh + ((size_t)17*64 + lane)*8);

  const f32x4 z = {0.f,0.f,0.f,0.f};
  f32x4 accQ[4] = {z,z,z,z};   // Q^T: rows e (tile w), cols Q-row (tile it)
  f32x4 accK[4] = {z,z,z,z};   // K^T: rows f (tile w), cols key (tile tt)
  f32x4 accV = z;

  #pragma unroll
  for (int it = 0; it < 4; ++it){
    accQ[it] = __builtin_amdgcn_mfma_f32_16x16x32_bf16(wq0, xa[it*2+0], accQ[it], 0,0,0);
    accQ[it] = __builtin_amdgcn_mfma_f32_16x16x32_bf16(wq1, xa[it*2+1], accQ[it], 0,0,0);
  }
  #pragma unroll
  for (int tt = 0; tt < 4; ++tt){
    accK[tt] = __builtin_amdgcn_mfma_f32_16x16x32_bf16(wk0, xa[tt*2+0], accK[tt], 0,0,0);
    accK[tt] = __builtin_amdgcn_mfma_f32_16x16x32_bf16(wk1, xa[tt*2+1], accK[tt], 0,0,0);
  }
  accV = __builtin_amdgcn_mfma_f32_16x16x32_bf16(xa[w*2+0], wv0, accV, 0,0,0);
  accV = __builtin_amdgcn_mfma_f32_16x16x32_bf16(xa[w*2+1], wv1, accV, 0,0,0);

  // ---- Q^T tiles: C[e=quad*4+reg (+w*16)][Qrow=l16] -> Qfr frag bytes
  {
    const int e0 = w*16 + quad*4;
    const float b0 = bql[e0], b1 = bql[e0+1], b2 = bql[e0+2], b3 = bql[e0+3];
    const int qk = (e0 & 31) >> 3, hf = e0 >> 5, boff = (quad & 1) * 4;
    #pragma unroll
    for (int it = 0; it < 4; ++it){
      unsigned o = pack_fp8x4(accQ[it][0]+b0, accQ[it][1]+b1,
                              accQ[it][2]+b2, accQ[it][3]+b3);
      const int T = (r0 >> 4) + it;
      *(unsigned*)(Qfr + (size_t)h*((size_t)n<<6) + (size_t)T*1024
                       + (qk*16 + l16)*16 + hf*8 + boff) = o;
    }
  }
  // ---- K^T tiles: C[f=quad*4+reg (+w*16)][key=l16] -> Kt frag bytes
  {
    const int f0 = w*16 + quad*4;
    const float bk0 = bkl[f0], bk1 = bkl[f0+1], bk2 = bkl[f0+2], bk3 = bkl[f0+3];
    const int qk = (f0 & 31) >> 3, hf = f0 >> 5, boff = (quad & 1) * 4;
    #pragma unroll
    for (int tt = 0; tt < 4; ++tt){
      unsigned o = pack_fp8x4(accK[tt][0]+bk0, accK[tt][1]+bk1,
                              accK[tt][2]+bk2, accK[tt][3]+bk3);
      const int T = (r0 >> 4) + tt;
      *(unsigned*)(Kt + (size_t)h*((size_t)n<<6) + (size_t)T*1024
                      + (qk*16 + l16)*16 + hf*8 + boff) = o;
    }
  }
  // ---- V tile (it=w): C[key=quad*4+reg][d=l16] == Vt lane(quad,l16), j=reg.
  // Chunk-interleaved store: chunk C=T>>1, half=(T&1) -> 8B slot within the
  // lane's 16B K=32 frag.
  {
    float bvv = bvl[l16];
    unsigned v01 = pack2bf(accV[0]+bvv, accV[1]+bvv);
    unsigned v23 = pack2bf(accV[2]+bvv, accV[3]+bvv);
    const int T = (r0 >> 4) + w;
    *(uint2*)(Vt + (size_t)h*((size_t)n<<4)
                 + ((size_t)(T>>1)*64 + lane)*8 + (T&1)*4) = make_uint2(v01, v23);
  }
}

// ---------------- flash attention kernel ----------------
// R18: TRAFFIC HALVING. Post-mortem R15-R17: attn time (~46us) was invariant
// under -25% matrix work, -15% VALU work, and -25% load count. Both pipes sat
// at ~50%. The invariant across all three was the vector-memory stream: every
// block reads its head's FULL K+V = 768KB from L2 (L1 thrashes; FETCH_SIZE
// shows it's not HBM). 1024 blocks -> 786MB = 17.1 TB/s = 27.9 B/cyc/CU of
// pure L1-miss traffic -- at/near the streaming L1<-L2 path ceiling.
// Fix: 64 Q-rows per block (grid halves to (n/64)*NH = 512 = 2 blocks/CU).
// K/V traffic halves at constant FLOPs; loads/chunk unchanged. Per chunk now
// 4 i-tiles, each a granule {4 QK-MFMA -> 8 exp2 -> 4 pack -> 2 PV-MFMA}:
// adjacent i-tile granules are independent, giving the scheduler MFMAs to
// overlap with exp2 latency. LDS part buffer 59KB -> exactly 2 blocks/CU.
__global__ __launch_bounds__(512, 4) void attn_kernel(
    const unsigned char* __restrict__ Qfr, const unsigned char* __restrict__ Kt,
    const unsigned short* __restrict__ Vt, float* __restrict__ out, int n)
{
  __shared__ float part[7][64][33];   // 59 KB padded (33: conflict-free)

  const int tid  = threadIdx.x;
  const int lane = tid & 63;
  const int jq   = tid >> 6;     // 0..7: key-range octant
  const int bid  = blockIdx.x;
  const int h    = bid & 3;
  const int iblk = bid >> 2;
  const int l16  = lane & 15, quad = lane >> 4;
  const int i0   = iblk*64;
  const int ntq  = (n >> 3) >> 4;            // 16-key tiles per octant (64)
  const int nch  = ntq >> 1;                 // 32-key chunks per octant (32)
  const int tile0 = jq * ntq;

  // Q fragments: 4 i-tiles x 2 e-halves -- DENSE (one uint4 per i-tile)
  const unsigned char* qfh = Qfr + (size_t)h*((size_t)n<<6);
  longlong2 q0 = *(const longlong2*)(qfh + (size_t)((i0>>4)    )*1024 + lane*16);
  longlong2 q1 = *(const longlong2*)(qfh + (size_t)((i0>>4) + 1)*1024 + lane*16);
  longlong2 q2 = *(const longlong2*)(qfh + (size_t)((i0>>4) + 2)*1024 + lane*16);
  longlong2 q3 = *(const longlong2*)(qfh + (size_t)((i0>>4) + 3)*1024 + lane*16);
  const fp8x8 qf00 = (fp8x8)q0.x, qf01 = (fp8x8)q0.y;
  const fp8x8 qf10 = (fp8x8)q1.x, qf11 = (fp8x8)q1.y;
  const fp8x8 qf20 = (fp8x8)q2.x, qf21 = (fp8x8)q2.y;
  const fp8x8 qf30 = (fp8x8)q3.x, qf31 = (fp8x8)q3.y;

  const longlong2* ktl = (const longlong2*)(Kt + (size_t)h*((size_t)n<<6)) + (size_t)tile0*64 + lane;
  const uint4*     vtu = (const uint4*)(Vt + (size_t)h*((size_t)n<<4)) + (size_t)(tile0>>1)*64 + lane;

  const f32x4 z = {0.f,0.f,0.f,0.f};
  f32x4 o0 = z, o1 = z, o2 = z, o3 = z;
  f32x4 la0 = z, la1 = z, la2 = z, la3 = z;
  const bf16x8 vones = {(short)0x3F80, (short)0x3F80, (short)0x3F80, (short)0x3F80,
                        (short)0x3F80, (short)0x3F80, (short)0x3F80, (short)0x3F80};

  // prologue: chunk 0 in A regs, chunk 1 in B regs
  longlong2 ka0 = ktl[0],   ka1 = ktl[64];
  uint4     va  = vtu[0];
  longlong2 kb0 = ktl[128], kb1 = ktl[192];
  uint4     vb  = vtu[64];

// one i-tile granule: 4 QK MFMAs -> 8 exp2 -> 4 packs -> 2 PV MFMAs.
// Adjacent granules are fully independent (ILP for MFMA/VALU overlap).
#define ITILE(QA, QB, OO, LL)                                                 \
  {                                                                           \
    f32x4 s = __builtin_amdgcn_mfma_f32_16x16x32_fp8_fp8(a0, QA, z, 0,0,0);   \
    s = __builtin_amdgcn_mfma_f32_16x16x32_fp8_fp8(a1, QB, s, 0,0,0);         \
    f32x4 u = __builtin_amdgcn_mfma_f32_16x16x32_fp8_fp8(b0, QA, z, 0,0,0);   \
    u = __builtin_amdgcn_mfma_f32_16x16x32_fp8_fp8(b1, QB, u, 0,0,0);         \
    float e0 = __builtin_amdgcn_exp2f(s[0]);                                  \
    float e1 = __builtin_amdgcn_exp2f(s[1]);                                  \
    float e2 = __builtin_amdgcn_exp2f(s[2]);                                  \
    float e3 = __builtin_amdgcn_exp2f(s[3]);                                  \
    float f0 = __builtin_amdgcn_exp2f(u[0]);                                  \
    float f1 = __builtin_amdgcn_exp2f(u[1]);                                  \
    float f2 = __builtin_amdgcn_exp2f(u[2]);                                  \
    float f3 = __builtin_amdgcn_exp2f(u[3]);                                  \
    union { uint4 uu; bf16x8 v; } pq;                                         \
    pq.uu = make_uint4(pack2bf_t(e0,e1), pack2bf_t(e2,e3),                    \
                       pack2bf_t(f0,f1), pack2bf_t(f2,f3));                   \
    OO = __builtin_amdgcn_mfma_f32_16x16x32_bf16(pq.v, vfv,   OO, 0,0,0);     \
    LL = __builtin_amdgcn_mfma_f32_16x16x32_bf16(pq.v, vones, LL, 0,0,0);     \
  }

#define ATTN_CHUNK(KA, KB, VV)                                                \
  {                                                                           \
    const fp8x8 a0 = (fp8x8)KA.x, a1 = (fp8x8)KA.y;                           \
    const fp8x8 b0 = (fp8x8)KB.x, b1 = (fp8x8)KB.y;                           \
    union { uint4 uu; bf16x8 v; } vfu; vfu.uu = VV;                           \
    const bf16x8 vfv = vfu.v;                                                 \
    ITILE(qf00, qf01, o0, la0)                                                \
    ITILE(qf10, qf11, o1, la1)                                                \
    ITILE(qf20, qf21, o2, la2)                                                \
    ITILE(qf30, qf31, o3, la3)                                                \
  }

  // main loop, unrolled x2: process chunk c from A regs then reload A with
  // chunk c+2; same for B with c+1/c+3. No register moves.
  for (int c = 0; c < nch - 2; c += 2){
    ATTN_CHUNK(ka0, ka1, va)
    ka0 = ktl[256]; ka1 = ktl[320]; va = vtu[128];
    ATTN_CHUNK(kb0, kb1, vb)
    kb0 = ktl[384]; kb1 = ktl[448]; vb = vtu[192];
    ktl += 256; vtu += 128;
  }
  // tail: last two chunks, no prefetch
  ATTN_CHUNK(ka0, ka1, va)
  ATTN_CHUNK(kb0, kb1, vb)
#undef ATTN_CHUNK
#undef ITILE

  if (jq > 0){
    float* p = &part[jq-1][lane][0];
    p[ 0]=o0[0];  p[ 1]=o0[1];  p[ 2]=o0[2];  p[ 3]=o0[3];
    p[ 4]=o1[0];  p[ 5]=o1[1];  p[ 6]=o1[2];  p[ 7]=o1[3];
    p[ 8]=o2[0];  p[ 9]=o2[1];  p[10]=o2[2];  p[11]=o2[3];
    p[12]=o3[0];  p[13]=o3[1];  p[14]=o3[2];  p[15]=o3[3];
    p[16]=la0[0]; p[17]=la0[1]; p[18]=la0[2]; p[19]=la0[3];
    p[20]=la1[0]; p[21]=la1[1]; p[22]=la1[2]; p[23]=la1[3];
    p[24]=la2[0]; p[25]=la2[1]; p[26]=la2[2]; p[27]=la2[3];
    p[28]=la3[0]; p[29]=la3[1]; p[30]=la3[2]; p[31]=la3[3];
  }
  __syncthreads();

  if (jq == 0){
    #pragma unroll
    for (int q = 0; q < 7; ++q){
      const float* r = &part[q][lane][0];
      o0[0] +=r[0];  o0[1] +=r[1];  o0[2] +=r[2];  o0[3] +=r[3];
      o1[0] +=r[4];  o1[1] +=r[5];  o1[2] +=r[6];  o1[3] +=r[7];
      o2[0] +=r[8];  o2[1] +=r[9];  o2[2] +=r[10]; o2[3] +=r[11];
      o3[0] +=r[12]; o3[1] +=r[13]; o3[2] +=r[14]; o3[3] +=r[15];
      la0[0]+=r[16]; la0[1]+=r[17]; la0[2]+=r[18]; la0[3]+=r[19];
      la1[0]+=r[20]; la1[1]+=r[21]; la1[2]+=r[22]; la1[3]+=r[23];
      la2[0]+=r[24]; la2[1]+=r[25]; la2[2]+=r[26]; la2[3]+=r[27];
      la3[0]+=r[28]; la3[1]+=r[29]; la3[2]+=r[30]; la3[3]+=r[31];
    }
    #pragma unroll
    for (int reg = 0; reg < 4; ++reg){
      int i = quad*4 + reg;
      out[(size_t)(i0 +      i)*64 + h*16 + l16] = o0[reg] / la0[reg];
      out[(size_t)(i0 + 16 + i)*64 + h*16 + l16] = o1[reg] / la1[reg];
      out[(size_t)(i0 + 32 + i)*64 + h*16 + l16] = o2[reg] / la2[reg];
      out[(size_t)(i0 + 48 + i)*64 + h*16 + l16] = o3[reg] / la3[reg];
    }
  }
}

extern "C" void kernel_launch(void* const* d_in, const int* in_sizes, int n_in,
                              void* d_out, int out_size, void* d_ws, size_t ws_size,
                              hipStream_t stream) {
  const float* x  = (const float*)d_in[0];
  const float* Wq = (const float*)d_in[1];
  const float* bq = (const float*)d_in[2];
  const float* Wk = (const float*)d_in[3];
  const float* bk = (const float*)d_in[4];
  const float* Wv = (const float*)d_in[5];
  const float* bv = (const float*)d_in[6];
  float* out = (float*)d_out;

  const int n = in_sizes[0] / 64;   // 8192

  unsigned char* Qfr  = (unsigned char*)d_ws;                       // NH*n*64 B frag tiles (Q)
  unsigned char* Kt   = Qfr + (size_t)NH*n*64;                      // NH*n*64 B frag tiles (K)
  unsigned short* Vt  = (unsigned short*)(Kt + (size_t)NH*n*64);    // NH*n*16 u16 frag tiles (chunk-interleaved)
  unsigned short* WF  = Vt + (size_t)NH*n*16;                       // NH*18*64*8 u16 frags
  float* bias_s       = (float*)(WF + (size_t)NH*18*64*8);          // NH*128 f32

  wprep_kernel<<<NH, 256, 0, stream>>>(Wq, bq, Wk, bk, Wv, WF, bias_s, n);
  proj_kernel<<<dim3(n/64, NH), 256, 0, stream>>>(x, bv, WF, bias_s, Qfr, Kt, Vt, n);
  attn_kernel<<<dim3((n/64)*NH), 512, 0, stream>>>(Qfr, Kt, Vt, out, n);
}

// Round 4
// 116.657 us; speedup vs baseline: 1.0495x; 1.0081x over previous
//
#include <hip/hip_runtime.h>

typedef __attribute__((ext_vector_type(4))) float f32x4;
typedef __attribute__((ext_vector_type(8))) short bf16x8;
typedef __attribute__((ext_vector_type(4))) short bf16x4;
typedef long fp8x8;   // 8 packed e4m3 bytes (i64 MFMA operand)

#define NH 4

// round-to-nearest-even f32 -> bf16
static __device__ __forceinline__ unsigned short f2bf(float f){
  unsigned u = __float_as_uint(f);
  u += 0x7FFFu + ((u >> 16) & 1u);
  return (unsigned short)(u >> 16);
}

// pack two f32 -> two bf16 (round-half-up) in one uint (low = a)
static __device__ __forceinline__ unsigned pack2bf(float a, float b){
  return __builtin_amdgcn_perm(__float_as_uint(b) + 0x8000u,
                               __float_as_uint(a) + 0x8000u, 0x07060302u);
}

// pack two f32 -> two bf16 TRUNCATING (1 v_perm). Used only for P: the same
// truncated P feeds both O=P*V and l=P*1, so the truncation bias cancels.
static __device__ __forceinline__ unsigned pack2bf_t(float a, float b){
  return __builtin_amdgcn_perm(__float_as_uint(b), __float_as_uint(a), 0x07060302u);
}

// pack 4 floats into 4 fp8(e4m3) bytes of one int (byte0 = a)
static __device__ __forceinline__ int pack_fp8x4(float a, float b, float c, float d){
  int w = __builtin_amdgcn_cvt_pk_fp8_f32(a, b, 0, false);
  w     = __builtin_amdgcn_cvt_pk_fp8_f32(c, d, w, true);
  return w;
}

// ---------------- weight-prep kernel (runs once per launch, 4 blocks) ------
// Per head: builds bf16 MFMA fragment-order W in ws + scaled biases.
// WF[h][s][lane][8bf16]:
//   s 0..7  = Wq^T A-frags (s=et*2+ks, pre-scaled S1):
//             lane(quad,l16) = Wq[ks*32+quad*8+j][et*16+l16], j=0..7
//   s 8..15 = Wk^T A-frags (s-8=ft*2+ks, pre-scaled S1): same mapping
//   s 16,17 = Wv B-frags: lane(quad,l16) = Wv[ks*32+quad*8+j][l16]
// bias_s[h][0..63]=bq*S1, [64..127]=bk*S1.
__global__ __launch_bounds__(256) void wprep_kernel(
    const float* __restrict__ Wq, const float* __restrict__ bq,
    const float* __restrict__ Wk, const float* __restrict__ bk,
    const float* __restrict__ Wv,
    unsigned short* __restrict__ WF, float* __restrict__ bias_s, int n)
{
  __shared__ unsigned short wqT[64*72];  // [e][f], stride 72 (16B-aligned rows)
  __shared__ unsigned short wkT[64*72];
  __shared__ unsigned short wvT[16*72];  // [d][f]

  const int t = threadIdx.x;     // 0..255
  const int h = blockIdx.x;
  const float S1 = 0.4246609001f; // sqrt((1/sqrt(64)) * log2(e))
  const int f = t >> 2, eg = t & 3;

  {
    const float4* g = (const float4*)(Wq + h*4096 + f*64 + eg*16);
    #pragma unroll
    for (int p = 0; p < 4; ++p){
      float4 d = g[p];
      int e0 = eg*16 + p*4;
      wqT[(e0+0)*72 + f] = f2bf(d.x * S1);
      wqT[(e0+1)*72 + f] = f2bf(d.y * S1);
      wqT[(e0+2)*72 + f] = f2bf(d.z * S1);
      wqT[(e0+3)*72 + f] = f2bf(d.w * S1);
    }
  }
  {
    const float4* g = (const float4*)(Wk + h*4096 + f*64 + eg*16);
    #pragma unroll
    for (int p = 0; p < 4; ++p){
      float4 d = g[p];
      int e0 = eg*16 + p*4;
      wkT[(e0+0)*72 + f] = f2bf(d.x * S1);
      wkT[(e0+1)*72 + f] = f2bf(d.y * S1);
      wkT[(e0+2)*72 + f] = f2bf(d.z * S1);
      wkT[(e0+3)*72 + f] = f2bf(d.w * S1);
    }
  }
  {
    float4 d = *(const float4*)(Wv + h*1024 + f*16 + eg*4);
    int d0 = eg*4;
    wvT[(d0+0)*72 + f] = f2bf(d.x);
    wvT[(d0+1)*72 + f] = f2bf(d.y);
    wvT[(d0+2)*72 + f] = f2bf(d.z);
    wvT[(d0+3)*72 + f] = f2bf(d.w);
  }
  if (t < 64)       bias_s[h*128 + t] = bq[h*64 + t] * S1;
  else if (t < 128) bias_s[h*128 + t] = bk[h*64 + (t-64)] * S1;
  __syncthreads();

  const int lane = t & 63, w = t >> 6;
  const int quad = lane >> 4, l16 = lane & 15;
  for (int s = w; s < 18; s += 4){
    const unsigned short* src;
    if (s < 8){      int et = s>>1,     ks = s&1;     src = wqT + (et*16+l16)*72 + ks*32 + quad*8; }
    else if (s < 16){int ft = (s-8)>>1, ks = (s-8)&1; src = wkT + (ft*16+l16)*72 + ks*32 + quad*8; }
    else {           int ks = s-16;                   src = wvT + l16*72 + ks*32 + quad*8; }
    uint4 v = *(const uint4*)src;
    *(uint4*)(WF + ((size_t)(h*18 + s)*64 + lane)*8) = v;
  }
}

// ---------------- projection kernel (MFMA) ----------------
// grid (n/64, NH), block 256 = 4 waves. Per wave: Q^T (e-tile w, 4 row-tiles),
// K^T (f-tile w, 4 key-tiles), V (row-tile w). Epilogue writes Qfr/Kt/Vt in
// fragment-tile order so ALL attn hot/prologue loads are dense.
// Vt is written CHUNK-interleaved (chunk C = pair of 16-key tiles):
// lane frag of tile T lands at (C*64+lane)*16B + (T&1)*8B, so attn's K=32 PV
// B-operand (32-key V frag) is ONE dense 16B load per lane.
__global__ __launch_bounds__(256) void proj_kernel(
    const float* __restrict__ x, const float* __restrict__ bv,
    const unsigned short* __restrict__ WF, const float* __restrict__ bias_s,
    unsigned char* __restrict__ Qfr, unsigned char* __restrict__ Kt,
    unsigned short* __restrict__ Vt, int n)
{
  __shared__ unsigned short xf[8*64*8];  // x frags: [it*2+ks][lane][8bf16]
  __shared__ float bql[64], bkl[64], bvl[16];

  const int t  = threadIdx.x;
  const int h  = blockIdx.y;
  const int r0 = blockIdx.x * 64;

  // stage x tile -> bf16 fragment order
  {
    const int r = t >> 2, cg4 = t & 3;
    const float4* g = (const float4*)(x + (size_t)(r0 + r)*64 + cg4*16);
    float4 a = g[0], b = g[1], c = g[2], d = g[3];
    unsigned u0 = pack2bf(a.x,a.y), u1 = pack2bf(a.z,a.w);
    unsigned u2 = pack2bf(b.x,b.y), u3 = pack2bf(b.z,b.w);
    unsigned u4 = pack2bf(c.x,c.y), u5 = pack2bf(c.z,c.w);
    unsigned u6 = pack2bf(d.x,d.y), u7 = pack2bf(d.z,d.w);
    const int it = r >> 4, l16r = r & 15, ks = cg4 >> 1, q0 = (cg4 & 1)*2;
    uint4* dst0 = (uint4*)(xf + ((it*2+ks)*64 + q0*16     + l16r)*8);
    uint4* dst1 = (uint4*)(xf + ((it*2+ks)*64 + (q0+1)*16 + l16r)*8);
    *dst0 = make_uint4(u0,u1,u2,u3);
    *dst1 = make_uint4(u4,u5,u6,u7);
  }
  if (t < 64)        bql[t]     = bias_s[h*128 + t];
  else if (t < 128)  bkl[t-64]  = bias_s[h*128 + t];
  else if (t < 144)  bvl[t-128] = bv[h*16 + (t-128)];
  __syncthreads();

  const int lane = t & 63, w = t >> 6;
  const int quad = lane >> 4, l16 = lane & 15;

  bf16x8 xa[8];
  #pragma unroll
  for (int i = 0; i < 8; ++i)
    xa[i] = *(const bf16x8*)(xf + (i*64 + lane)*8);

  const unsigned short* WFh = WF + (size_t)h*18*64*8;
  bf16x8 wq0 = *(const bf16x8*)(WFh + ((size_t)(     w*2 + 0)*64 + lane)*8);
  bf16x8 wq1 = *(const bf16x8*)(WFh + ((size_t)(     w*2 + 1)*64 + lane)*8);
  bf16x8 wk0 = *(const bf16x8*)(WFh + ((size_t)(8  + w*2 + 0)*64 + lane)*8);
  bf16x8 wk1 = *(const bf16x8*)(WFh + ((size_t)(8  + w*2 + 1)*64 + lane)*8);
  bf16x8 wv0 = *(const bf16x8*)(WFh + ((size_t)16*64 + lane)*8);
  bf16x8 wv1 = *(const bf16x8*)(WFh + ((size_t)17*64 + lane)*8);

  const f32x4 z = {0.f,0.f,0.f,0.f};
  f32x4 accQ[4] = {z,z,z,z};   // Q^T: rows e (tile w), cols Q-row (tile it)
  f32x4 accK[4] = {z,z,z,z};   // K^T: rows f (tile w), cols key (tile tt)
  f32x4 accV = z;

  #pragma unroll
  for (int it = 0; it < 4; ++it){
    accQ[it] = __builtin_amdgcn_mfma_f32_16x16x32_bf16(wq0, xa[it*2+0], accQ[it], 0,0,0);
    accQ[it] = __builtin_amdgcn_mfma_f32_16x16x32_bf16(wq1, xa[it*2+1], accQ[it], 0,0,0);
  }
  #pragma unroll
  for (int tt = 0; tt < 4; ++tt){
    accK[tt] = __builtin_amdgcn_mfma_f32_16x16x32_bf16(wk0, xa[tt*2+0], accK[tt], 0,0,0);
    accK[tt] = __builtin_amdgcn_mfma_f32_16x16x32_bf16(wk1, xa[tt*2+1], accK[tt], 0,0,0);
  }
  accV = __builtin_amdgcn_mfma_f32_16x16x32_bf16(xa[w*2+0], wv0, accV, 0,0,0);
  accV = __builtin_amdgcn_mfma_f32_16x16x32_bf16(xa[w*2+1], wv1, accV, 0,0,0);

  // ---- Q^T tiles: C[e=quad*4+reg (+w*16)][Qrow=l16] -> Qfr frag bytes
  {
    const int e0 = w*16 + quad*4;
    const float b0 = bql[e0], b1 = bql[e0+1], b2 = bql[e0+2], b3 = bql[e0+3];
    const int qk = (e0 & 31) >> 3, hf = e0 >> 5, boff = (quad & 1) * 4;
    #pragma unroll
    for (int it = 0; it < 4; ++it){
      unsigned o = pack_fp8x4(accQ[it][0]+b0, accQ[it][1]+b1,
                              accQ[it][2]+b2, accQ[it][3]+b3);
      const int T = (r0 >> 4) + it;
      *(unsigned*)(Qfr + (size_t)h*((size_t)n<<6) + (size_t)T*1024
                       + (qk*16 + l16)*16 + hf*8 + boff) = o;
    }
  }
  // ---- K^T tiles: C[f=quad*4+reg (+w*16)][key=l16] -> Kt frag bytes
  {
    const int f0 = w*16 + quad*4;
    const float bk0 = bkl[f0], bk1 = bkl[f0+1], bk2 = bkl[f0+2], bk3 = bkl[f0+3];
    const int qk = (f0 & 31) >> 3, hf = f0 >> 5, boff = (quad & 1) * 4;
    #pragma unroll
    for (int tt = 0; tt < 4; ++tt){
      unsigned o = pack_fp8x4(accK[tt][0]+bk0, accK[tt][1]+bk1,
                              accK[tt][2]+bk2, accK[tt][3]+bk3);
      const int T = (r0 >> 4) + tt;
      *(unsigned*)(Kt + (size_t)h*((size_t)n<<6) + (size_t)T*1024
                      + (qk*16 + l16)*16 + hf*8 + boff) = o;
    }
  }
  // ---- V tile (it=w): C[key=quad*4+reg][d=l16] == Vt lane(quad,l16), j=reg.
  // Chunk-interleaved store: chunk C=T>>1, half=(T&1) -> 8B slot within the
  // lane's 16B K=32 frag.
  {
    float bvv = bvl[l16];
    unsigned v01 = pack2bf(accV[0]+bvv, accV[1]+bvv);
    unsigned v23 = pack2bf(accV[2]+bvv, accV[3]+bvv);
    const int T = (r0 >> 4) + w;
    *(uint2*)(Vt + (size_t)h*((size_t)n<<4)
                 + ((size_t)(T>>1)*64 + lane)*8 + (T&1)*4) = make_uint2(v01, v23);
  }
}

// ---------------- flash attention kernel ----------------
// R19: SCHEDULE FORCING (zero numeric change vs R18). Post-mortem R15-R18:
// attn time (~46-47us) invariant under -25% matrix work, -15% VALU count,
// -25% loads, -50% L2 traffic, and 2x occupancy. No pipe is saturated
// (MfmaUtil 43, VALUBusy 50). Leading theory: PHASE-LOCK -- all waves run
// the same [MFMA burst | exp2/pack burst] alternation in lockstep (launched
// together, correlated vmcnt waits), so the SIMD alternates starved pipes
// and time ~ per-phase serial sum, insensitive to wave count (R15==R18) and
// to trimming one phase. Supporting: R11's added VALU cost +68% while R17's
// removed VALU moved nothing -- the VALU phase gates an alternating schedule.
// Two levers, both numerics-free:
//  (1) sched_group_barrier pipeline 16x{3 MFMA, 6 VALU} per 2-chunk body
//      (48 MFMA : ~96 VALU) -- forces granule g+1's QK MFMAs under granule
//      g's exp2/pack, co-busying matrix+VALU pipes within one wave.
//  (2) jq-proportional s_sleep stagger at kernel start -- decorrelates
//      sibling waves' burst phases for inter-wave overlap.
__global__ __launch_bounds__(512, 4) void attn_kernel(
    const unsigned char* __restrict__ Qfr, const unsigned char* __restrict__ Kt,
    const unsigned short* __restrict__ Vt, float* __restrict__ out, int n)
{
  __shared__ float part[7][64][33];   // 59 KB padded (33: conflict-free)

  const int tid  = threadIdx.x;
  const int lane = tid & 63;
  const int jq   = tid >> 6;     // 0..7: key-range octant

  // (2) wave phase-stagger: ~220 cyc per jq step, before any memory op.
  #pragma unroll 1
  for (int i = 0; i < jq; ++i) __builtin_amdgcn_s_sleep(3);

  const int bid  = blockIdx.x;
  const int h    = bid & 3;
  const int iblk = bid >> 2;
  const int l16  = lane & 15, quad = lane >> 4;
  const int i0   = iblk*64;
  const int ntq  = (n >> 3) >> 4;            // 16-key tiles per octant (64)
  const int nch  = ntq >> 1;                 // 32-key chunks per octant (32)
  const int tile0 = jq * ntq;

  // Q fragments: 4 i-tiles x 2 e-halves -- DENSE (one uint4 per i-tile)
  const unsigned char* qfh = Qfr + (size_t)h*((size_t)n<<6);
  longlong2 q0 = *(const longlong2*)(qfh + (size_t)((i0>>4)    )*1024 + lane*16);
  longlong2 q1 = *(const longlong2*)(qfh + (size_t)((i0>>4) + 1)*1024 + lane*16);
  longlong2 q2 = *(const longlong2*)(qfh + (size_t)((i0>>4) + 2)*1024 + lane*16);
  longlong2 q3 = *(const longlong2*)(qfh + (size_t)((i0>>4) + 3)*1024 + lane*16);
  const fp8x8 qf00 = (fp8x8)q0.x, qf01 = (fp8x8)q0.y;
  const fp8x8 qf10 = (fp8x8)q1.x, qf11 = (fp8x8)q1.y;
  const fp8x8 qf20 = (fp8x8)q2.x, qf21 = (fp8x8)q2.y;
  const fp8x8 qf30 = (fp8x8)q3.x, qf31 = (fp8x8)q3.y;

  const longlong2* ktl = (const longlong2*)(Kt + (size_t)h*((size_t)n<<6)) + (size_t)tile0*64 + lane;
  const uint4*     vtu = (const uint4*)(Vt + (size_t)h*((size_t)n<<4)) + (size_t)(tile0>>1)*64 + lane;

  const f32x4 z = {0.f,0.f,0.f,0.f};
  f32x4 o0 = z, o1 = z, o2 = z, o3 = z;
  f32x4 la0 = z, la1 = z, la2 = z, la3 = z;
  const bf16x8 vones = {(short)0x3F80, (short)0x3F80, (short)0x3F80, (short)0x3F80,
                        (short)0x3F80, (short)0x3F80, (short)0x3F80, (short)0x3F80};

  // prologue: chunk 0 in A regs, chunk 1 in B regs
  longlong2 ka0 = ktl[0],   ka1 = ktl[64];
  uint4     va  = vtu[0];
  longlong2 kb0 = ktl[128], kb1 = ktl[192];
  uint4     vb  = vtu[64];

// one i-tile granule: 4 QK MFMAs -> 8 exp2 -> 4 packs -> 2 PV MFMAs.
// Adjacent granules are fully independent (ILP for MFMA/VALU overlap).
#define ITILE(QA, QB, OO, LL)                                                 \
  {                                                                           \
    f32x4 s = __builtin_amdgcn_mfma_f32_16x16x32_fp8_fp8(a0, QA, z, 0,0,0);   \
    s = __builtin_amdgcn_mfma_f32_16x16x32_fp8_fp8(a1, QB, s, 0,0,0);         \
    f32x4 u = __builtin_amdgcn_mfma_f32_16x16x32_fp8_fp8(b0, QA, z, 0,0,0);   \
    u = __builtin_amdgcn_mfma_f32_16x16x32_fp8_fp8(b1, QB, u, 0,0,0);         \
    float e0 = __builtin_amdgcn_exp2f(s[0]);                                  \
    float e1 = __builtin_amdgcn_exp2f(s[1]);                                  \
    float e2 = __builtin_amdgcn_exp2f(s[2]);                                  \
    float e3 = __builtin_amdgcn_exp2f(s[3]);                                  \
    float f0 = __builtin_amdgcn_exp2f(u[0]);                                  \
    float f1 = __builtin_amdgcn_exp2f(u[1]);                                  \
    float f2 = __builtin_amdgcn_exp2f(u[2]);                                  \
    float f3 = __builtin_amdgcn_exp2f(u[3]);                                  \
    union { uint4 uu; bf16x8 v; } pq;                                         \
    pq.uu = make_uint4(pack2bf_t(e0,e1), pack2bf_t(e2,e3),                    \
                       pack2bf_t(f0,f1), pack2bf_t(f2,f3));                   \
    OO = __builtin_amdgcn_mfma_f32_16x16x32_bf16(pq.v, vfv,   OO, 0,0,0);     \
    LL = __builtin_amdgcn_mfma_f32_16x16x32_bf16(pq.v, vones, LL, 0,0,0);     \
  }

#define ATTN_CHUNK(KA, KB, VV)                                                \
  {                                                                           \
    const fp8x8 a0 = (fp8x8)KA.x, a1 = (fp8x8)KA.y;                           \
    const fp8x8 b0 = (fp8x8)KB.x, b1 = (fp8x8)KB.y;                           \
    union { uint4 uu; bf16x8 v; } vfu; vfu.uu = VV;                           \
    const bf16x8 vfv = vfu.v;                                                 \
    ITILE(qf00, qf01, o0, la0)                                                \
    ITILE(qf10, qf11, o1, la1)                                                \
    ITILE(qf20, qf21, o2, la2)                                                \
    ITILE(qf30, qf31, o3, la3)                                                \
  }

  // main loop, unrolled x2: process chunk c from A regs then reload A with
  // chunk c+2; same for B with c+1/c+3. No register moves.
  for (int c = 0; c < nch - 2; c += 2){
    ATTN_CHUNK(ka0, ka1, va)
    ka0 = ktl[256]; ka1 = ktl[320]; va = vtu[128];
    ATTN_CHUNK(kb0, kb1, vb)
    kb0 = ktl[384]; kb1 = ktl[448]; vb = vtu[192];
    ktl += 256; vtu += 128;
    // (1) pipeline directive: per 2-chunk body, 48 MFMA : ~96 VALU arranged
    // as 16 x {3 MFMA, 6 VALU} -- ~48cy matrix vs ~48cy VALU per pattern,
    // forcing the pipes to run concurrently. Loads/SALU float freely.
    #pragma unroll
    for (int g = 0; g < 16; ++g){
      __builtin_amdgcn_sched_group_barrier(0x008, 3, 0);  // 3 MFMA
      __builtin_amdgcn_sched_group_barrier(0x002, 6, 0);  // 6 VALU
    }
  }
  // tail: last two chunks, no prefetch
  ATTN_CHUNK(ka0, ka1, va)
  ATTN_CHUNK(kb0, kb1, vb)
#undef ATTN_CHUNK
#undef ITILE

  if (jq > 0){
    float* p = &part[jq-1][lane][0];
    p[ 0]=o0[0];  p[ 1]=o0[1];  p[ 2]=o0[2];  p[ 3]=o0[3];
    p[ 4]=o1[0];  p[ 5]=o1[1];  p[ 6]=o1[2];  p[ 7]=o1[3];
    p[ 8]=o2[0];  p[ 9]=o2[1];  p[10]=o2[2];  p[11]=o2[3];
    p[12]=o3[0];  p[13]=o3[1];  p[14]=o3[2];  p[15]=o3[3];
    p[16]=la0[0]; p[17]=la0[1]; p[18]=la0[2]; p[19]=la0[3];
    p[20]=la1[0]; p[21]=la1[1]; p[22]=la1[2]; p[23]=la1[3];
    p[24]=la2[0]; p[25]=la2[1]; p[26]=la2[2]; p[27]=la2[3];
    p[28]=la3[0]; p[29]=la3[1]; p[30]=la3[2]; p[31]=la3[3];
  }
  __syncthreads();

  if (jq == 0){
    #pragma unroll
    for (int q = 0; q < 7; ++q){
      const float* r = &part[q][lane][0];
      o0[0] +=r[0];  o0[1] +=r[1];  o0[2] +=r[2];  o0[3] +=r[3];
      o1[0] +=r[4];  o1[1] +=r[5];  o1[2] +=r[6];  o1[3] +=r[7];
      o2[0] +=r[8];  o2[1] +=r[9];  o2[2] +=r[10]; o2[3] +=r[11];
      o3[0] +=r[12]; o3[1] +=r[13]; o3[2] +=r[14]; o3[3] +=r[15];
      la0[0]+=r[16]; la0[1]+=r[17]; la0[2]+=r[18]; la0[3]+=r[19];
      la1[0]+=r[20]; la1[1]+=r[21]; la1[2]+=r[22]; la1[3]+=r[23];
      la2[0]+=r[24]; la2[1]+=r[25]; la2[2]+=r[26]; la2[3]+=r[27];
      la3[0]+=r[28]; la3[1]+=r[29]; la3[2]+=r[30]; la3[3]+=r[31];
    }
    #pragma unroll
    for (int reg = 0; reg < 4; ++reg){
      int i = quad*4 + reg;
      out[(size_t)(i0 +      i)*64 + h*16 + l16] = o0[reg] / la0[reg];
      out[(size_t)(i0 + 16 + i)*64 + h*16 + l16] = o1[reg] / la1[reg];
      out[(size_t)(i0 + 32 + i)*64 + h*16 + l16] = o2[reg] / la2[reg];
      out[(size_t)(i0 + 48 + i)*64 + h*16 + l16] = o3[reg] / la3[reg];
    }
  }
}

extern "C" void kernel_launch(void* const* d_in, const int* in_sizes, int n_in,
                              void* d_out, int out_size, void* d_ws, size_t ws_size,
                              hipStream_t stream) {
  const float* x  = (const float*)d_in[0];
  const float* Wq = (const float*)d_in[1];
  const float* bq = (const float*)d_in[2];
  const float* Wk = (const float*)d_in[3];
  const float* bk = (const float*)d_in[4];
  const float* Wv = (const float*)d_in[5];
  const float* bv = (const float*)d_in[6];
  float* out = (float*)d_out;

  const int n = in_sizes[0] / 64;   // 8192

  unsigned char* Qfr  = (unsigned char*)d_ws;                       // NH*n*64 B frag tiles (Q)
  unsigned char* Kt   = Qfr + (size_t)NH*n*64;                      // NH*n*64 B frag tiles (K)
  unsigned short* Vt  = (unsigned short*)(Kt + (size_t)NH*n*64);    // NH*n*16 u16 frag tiles (chunk-interleaved)
  unsigned short* WF  = Vt + (size_t)NH*n*16;                       // NH*18*64*8 u16 frags
  float* bias_s       = (float*)(WF + (size_t)NH*18*64*8);          // NH*128 f32

  wprep_kernel<<<NH, 256, 0, stream>>>(Wq, bq, Wk, bk, Wv, WF, bias_s, n);
  proj_kernel<<<dim3(n/64, NH), 256, 0, stream>>>(x, bv, WF, bias_s, Qfr, Kt, Vt, n);
  attn_kernel<<<dim3((n/64)*NH), 512, 0, stream>>>(Qfr, Kt, Vt, out, n);
}